// Round 1
// baseline (94.947 us; speedup 1.0000x reference)
//
#include <hip/hip_runtime.h>

// B=32, G=512
// out layout: [rel_pos (B,G,G,3) | rel_ori (B,G,G,3,3)] flat f32

#define GG 512

__global__ __launch_bounds__(256) void relposori_kernel(
    const float* __restrict__ center,   // (B,G,6)
    const float* __restrict__ lrf,      // (B,G,3,3)
    float* __restrict__ out_pos,        // (B,G,G,3)
    float* __restrict__ out_ori)        // (B,G,G,3,3)
{
    // blockIdx.x = (b*G + i)*2 + jhalf ; 2 blocks of 256 j's per (b,i)
    int blk   = blockIdx.x;
    int jhalf = blk & 1;
    int bi    = blk >> 1;          // b*G + i  (uniform within block)
    int b     = bi >> 9;
    int j     = (jhalf << 8) | threadIdx.x;

    // uniform (scalar) loads: center_i and lrf_i
    const float* ci = center + (size_t)bi * 6;
    const float* li = lrf    + (size_t)bi * 9;
    float ci0 = ci[0], ci1 = ci[1], ci2 = ci[2];
    float li_[9];
#pragma unroll
    for (int t = 0; t < 9; ++t) li_[t] = li[t];

    size_t bj = (size_t)b * GG + j;
    const float* cj = center + bj * 6;
    const float* lj = lrf    + bj * 9;
    float d0 = cj[0] - ci0, d1 = cj[1] - ci1, d2 = cj[2] - ci2;
    float lj_[9];
#pragma unroll
    for (int t = 0; t < 9; ++t) lj_[t] = lj[t];

    // rel_pos[k] = sum_c d[c] * lrf_i[c][k]
    float rp[3];
#pragma unroll
    for (int k = 0; k < 3; ++k)
        rp[k] = d0 * li_[k] + d1 * li_[3 + k] + d2 * li_[6 + k];

    // rel_ori[m][n] = sum_k lrf_i[k][m] * lrf_j[k][n]
    float ro[9];
#pragma unroll
    for (int m = 0; m < 3; ++m)
#pragma unroll
        for (int n = 0; n < 3; ++n)
            ro[m * 3 + n] = li_[m]     * lj_[n]
                          + li_[3 + m] * lj_[3 + n]
                          + li_[6 + m] * lj_[6 + n];

    size_t pair = (size_t)bi * GG + j;
    float* op = out_pos + pair * 3;
    op[0] = rp[0]; op[1] = rp[1]; op[2] = rp[2];

    float* oo = out_ori + pair * 9;
#pragma unroll
    for (int t = 0; t < 9; ++t) oo[t] = ro[t];
}

extern "C" void kernel_launch(void* const* d_in, const int* in_sizes, int n_in,
                              void* d_out, int out_size, void* d_ws, size_t ws_size,
                              hipStream_t stream) {
    const float* center = (const float*)d_in[0];
    const float* lrf    = (const float*)d_in[1];
    float* out = (float*)d_out;

    const int B = 32;
    const size_t n_pos = (size_t)B * GG * GG * 3;   // 25,165,824
    float* out_pos = out;
    float* out_ori = out + n_pos;

    dim3 grid(B * GG * 2);
    dim3 block(256);
    hipLaunchKernelGGL(relposori_kernel, grid, block, 0, stream,
                       center, lrf, out_pos, out_ori);
}

// Round 2
// 73.214 us; speedup vs baseline: 1.2969x; 1.2969x over previous
//
#include <hip/hip_runtime.h>

// B=32, G=512
// out layout: [rel_pos (B,G,G,3) | rel_ori (B,G,G,3,3)] flat f32

#define GG 512

__global__ __launch_bounds__(256) void relposori_kernel(
    const float* __restrict__ center,   // (B,G,6)
    const float* __restrict__ lrf,      // (B,G,3,3)
    float* __restrict__ out_pos,        // (B,G,G,3)
    float* __restrict__ out_ori)        // (B,G,G,3,3)
{
    __shared__ float s_pos[GG * 3];   // 6144 B, row laid out as output
    __shared__ float s_ori[GG * 9];   // 18432 B

    int bi  = blockIdx.x;             // b*G + i  (uniform within block)
    int b   = bi >> 9;
    int tid = threadIdx.x;

    // uniform (scalar) loads: center_i and lrf_i
    const float* ci = center + (size_t)bi * 6;
    const float* li = lrf    + (size_t)bi * 9;
    float ci0 = ci[0], ci1 = ci[1], ci2 = ci[2];
    float li_[9];
#pragma unroll
    for (int t = 0; t < 9; ++t) li_[t] = li[t];

#pragma unroll
    for (int jj = 0; jj < 2; ++jj) {
        int j = tid + (jj << 8);
        size_t bj = (size_t)b * GG + j;
        const float* cj = center + bj * 6;
        const float* lj = lrf    + bj * 9;
        float d0 = cj[0] - ci0, d1 = cj[1] - ci1, d2 = cj[2] - ci2;
        float lj_[9];
#pragma unroll
        for (int t = 0; t < 9; ++t) lj_[t] = lj[t];

        // rel_pos[k] = sum_c d[c] * lrf_i[c][k]
#pragma unroll
        for (int k = 0; k < 3; ++k)
            s_pos[j * 3 + k] = d0 * li_[k] + d1 * li_[3 + k] + d2 * li_[6 + k];

        // rel_ori[m][n] = sum_k lrf_i[k][m] * lrf_j[k][n]
#pragma unroll
        for (int m = 0; m < 3; ++m)
#pragma unroll
            for (int n = 0; n < 3; ++n)
                s_ori[j * 9 + m * 3 + n] = li_[m]     * lj_[n]
                                         + li_[3 + m] * lj_[3 + n]
                                         + li_[6 + m] * lj_[6 + n];
    }

    __syncthreads();

    // Coalesced, 16B-aligned float4 writeback of the whole row.
    const float4* sp4 = (const float4*)s_pos;
    float4*       op4 = (float4*)(out_pos + (size_t)bi * (GG * 3));
#pragma unroll
    for (int t = tid; t < GG * 3 / 4; t += 256)   // 384 float4
        op4[t] = sp4[t];

    const float4* so4 = (const float4*)s_ori;
    float4*       oo4 = (float4*)(out_ori + (size_t)bi * (GG * 9));
#pragma unroll
    for (int t = tid; t < GG * 9 / 4; t += 256)   // 1152 float4
        oo4[t] = so4[t];
}

extern "C" void kernel_launch(void* const* d_in, const int* in_sizes, int n_in,
                              void* d_out, int out_size, void* d_ws, size_t ws_size,
                              hipStream_t stream) {
    const float* center = (const float*)d_in[0];
    const float* lrf    = (const float*)d_in[1];
    float* out = (float*)d_out;

    const int B = 32;
    const size_t n_pos = (size_t)B * GG * GG * 3;   // 25,165,824 floats
    float* out_pos = out;
    float* out_ori = out + n_pos;

    dim3 grid(B * GG);    // one block per (b,i) row
    dim3 block(256);
    hipLaunchKernelGGL(relposori_kernel, grid, block, 0, stream,
                       center, lrf, out_pos, out_ori);
}